// Round 17
// baseline (130.303 us; speedup 1.0000x reference)
//
#include <hip/hip_runtime.h>
#include <cstdint>

#define B_SZ   16384
#define H_SZ   512
#define DIN    256
#define TEMB   16
#define KP     1344            // packed K: x[0,256) h[256,768) c[768,1280) delt[1280,1296) pad
#define KPB    1344            // bytes per row (i8)
#define BH     8388608L        // B_SZ*H_SZ
#define SLOT   24576           // main slot: A 16 KB (256 rows x 64 B) + 4 W regions x 2 KB
#define TSLOT  20480           // tgate slot: A 16 KB + 2 W regions x 2 KB
#define GSTR   688128          // 512*KPB: gate stride in Wp8 bytes

typedef __attribute__((ext_vector_type(4))) float f32x4;
typedef __attribute__((ext_vector_type(4))) int   i32x4;

typedef const __attribute__((address_space(1))) unsigned int gu32_t;
typedef __attribute__((address_space(3)))       unsigned int lu32_t;

__device__ __forceinline__ void gld16(const void* g, void* l) {
  __builtin_amdgcn_global_load_lds((gu32_t*)(uintptr_t)g,
                                   (lu32_t*)(unsigned int)(uintptr_t)l, 16, 0, 0);
}

__device__ __forceinline__ float sigm(float v)  { return 1.0f / (1.0f + __expf(-v)); }
__device__ __forceinline__ float tanhx(float v) { return 2.0f / (1.0f + __expf(-2.0f * v)) - 1.0f; }

__device__ __forceinline__ signed char q8(float v, float inv) {
  int q = __float2int_rn(v * inv);
  q = (q > 127) ? 127 : (q < -127 ? -127 : q);
  return (signed char)q;
}

// ---------------- prep: quantize A rows = [x|h|c|delt|0] to i8 + row scale ----------------
__global__ void prep_a8_kernel(const float* __restrict__ x, const float* __restrict__ h,
                               const float* __restrict__ c, const float* __restrict__ dl,
                               signed char* __restrict__ Ap, float* __restrict__ sa) {
  __shared__ float row[KP];
  __shared__ float red[256];
  const int m   = blockIdx.x;
  const int tid = threadIdx.x;
  float lmax = 0.f;
  for (int i = tid; i < KP / 4; i += 256) {
    const int k4 = i * 4;
    float4 v = make_float4(0.f, 0.f, 0.f, 0.f);
    if (k4 < 256)       v = *(const float4*)(x  + (size_t)m * DIN  + k4);
    else if (k4 < 768)  v = *(const float4*)(h  + (size_t)m * H_SZ + (k4 - 256));
    else if (k4 < 1280) v = *(const float4*)(c  + (size_t)m * H_SZ + (k4 - 768));
    else if (k4 < 1296) v = *(const float4*)(dl + (size_t)m * TEMB + (k4 - 1280));
    *(float4*)(row + k4) = v;
    lmax = fmaxf(lmax, fmaxf(fmaxf(fabsf(v.x), fabsf(v.y)), fmaxf(fabsf(v.z), fabsf(v.w))));
  }
  red[tid] = lmax;
  __syncthreads();
  for (int s = 128; s > 0; s >>= 1) {
    if (tid < s) red[tid] = fmaxf(red[tid], red[tid + s]);
    __syncthreads();
  }
  const float smax = fmaxf(red[0], 1e-20f);
  const float inv  = 127.0f / smax;
  if (tid == 0) sa[m] = smax * (1.0f / 127.0f);
  for (int i = tid; i < KP / 4; i += 256) {
    const int k4 = i * 4;
    char4 o;
    o.x = q8(row[k4],     inv); o.y = q8(row[k4 + 1], inv);
    o.z = q8(row[k4 + 2], inv); o.w = q8(row[k4 + 3], inv);
    *(char4*)(Ap + (size_t)m * KPB + k4) = o;
  }
}

// ---------------- prep: quantize Wp8[6][512][KP] i8 + per-row scale ----------------
__global__ void prep_w8_kernel(const float* __restrict__ Wix, const float* __restrict__ Wih, const float* __restrict__ Wic,
                               const float* __restrict__ Wfx, const float* __restrict__ Wfh, const float* __restrict__ Wfc,
                               const float* __restrict__ Wtx, const float* __restrict__ Wtt,
                               const float* __restrict__ Wcx, const float* __restrict__ Wch,
                               const float* __restrict__ Wox, const float* __restrict__ Woh,
                               const float* __restrict__ Woc, const float* __restrict__ Wot,
                               signed char* __restrict__ Wp, float* __restrict__ sw) {
  __shared__ float row[KP];
  __shared__ float red[256];
  const int R   = blockIdx.x;        // 0..3071
  const int g   = R >> 9;
  const int n   = R & 511;
  const int tid = threadIdx.x;
  float lmax = 0.f;
  for (int i = tid; i < KP / 4; i += 256) {
    const int k4 = i * 4;
    const float* src = nullptr; long o = 0;
    if (g == 0) {
      if (k4 < 256)       { src = Wix; o = (long)n * 256 + k4; }
      else if (k4 < 768)  { src = Wih; o = (long)n * 512 + (k4 - 256); }
      else if (k4 < 1280) { src = Wic; o = (long)n * 512 + (k4 - 768); }
    } else if (g == 1) {
      if (k4 < 256)       { src = Wfx; o = (long)n * 256 + k4; }
      else if (k4 < 768)  { src = Wfh; o = (long)n * 512 + (k4 - 256); }
      else if (k4 < 1280) { src = Wfc; o = (long)n * 512 + (k4 - 768); }
    } else if (g == 2) {
      if (k4 < 256)       { src = Wtx; o = (long)n * 256 + k4; }
    } else if (g == 3) {
      if (k4 < 256)       { src = Wcx; o = (long)n * 256 + k4; }
      else if (k4 < 768)  { src = Wch; o = (long)n * 512 + (k4 - 256); }
    } else if (g == 4) {
      if (k4 < 256)       { src = Wox; o = (long)n * 256 + k4; }
      else if (k4 < 768)  { src = Woh; o = (long)n * 512 + (k4 - 256); }
      else if (k4 < 1280) { src = Woc; o = (long)n * 512 + (k4 - 768); }
      else if (k4 < 1296) { src = Wot; o = (long)n * 16 + (k4 - 1280); }
    } else {
      if (k4 >= 1280 && k4 < 1296) { src = Wtt; o = (long)n * 16 + (k4 - 1280); }
    }
    float4 v = make_float4(0.f, 0.f, 0.f, 0.f);
    if (src) v = *(const float4*)(src + o);
    *(float4*)(row + k4) = v;
    lmax = fmaxf(lmax, fmaxf(fmaxf(fabsf(v.x), fabsf(v.y)), fmaxf(fabsf(v.z), fabsf(v.w))));
  }
  red[tid] = lmax;
  __syncthreads();
  for (int s = 128; s > 0; s >>= 1) {
    if (tid < s) red[tid] = fmaxf(red[tid], red[tid + s]);
    __syncthreads();
  }
  const float smax = fmaxf(red[0], 1e-20f);
  const float inv  = 127.0f / smax;
  if (tid == 0) sw[R] = smax * (1.0f / 127.0f);
  for (int i = tid; i < KP / 4; i += 256) {
    const int k4 = i * 4;
    char4 o;
    o.x = q8(row[k4],     inv); o.y = q8(row[k4 + 1], inv);
    o.z = q8(row[k4 + 2], inv); o.w = q8(row[k4 + 3], inv);
    *(char4*)(Wp + (size_t)R * KPB + k4) = o;
  }
}

// LDS layout per slot (K-phase = 64 i8 = 64 B per row; byte math r11/r16-verified):
//   A: byte = row*64 + ((kgrp + (lrow>>1))&3)*16,  row in [0,256)
//   W: byte = 16384 + region*2048 + col*64 + swz,  col in [0,32)
// gld16 writes 1KB chunks linearly; per-lane source granule pre-permuted (kslot).

// ---------------- main staging: regions {0,1,2,3} = gates {i=0,f=1,k=3,o=4} ----------------
// A: wave w -> chunks {2w,2w+1} (rows [32w,32w+32)).  W: chunk (r,c) -> wave 2r+c.
template<unsigned SMASK>
__device__ __forceinline__ void stage(char* lds, int sb, int ht,
                                      const char* sAb, const char* sWb, int wid) {
  const unsigned kb = (unsigned)ht * 64u;
  gld16(sAb + kb,              lds + sb + wid * 2048);
  gld16(sAb + kb + 16u * KPB,  lds + sb + wid * 2048 + 1024);
  const int r = wid >> 1, c = wid & 1;        // region, col-half (wave-uniform)
  if (SMASK & (1u << r)) {
    const int g = r + (r >> 1);               // region -> gate: 0,1,3,4
    gld16(sWb + (unsigned)g * GSTR + (unsigned)c * (16u * KPB) + kb,
          lds + sb + 16384 + r * 2048 + c * 1024);
  }
}

template<unsigned CM>
__device__ __forceinline__ void comp(const char* lds, int sb, int aro, int wro,
                                     i32x4 acc[4][4]) {
  const char* base = lds + sb;
  i32x4 a[4];
#pragma unroll
  for (int i = 0; i < 4; ++i)
    a[i] = *(const i32x4*)(base + aro + i * 1024);
  __builtin_amdgcn_s_setprio(1);
#pragma unroll
  for (int r = 0; r < 4; ++r) {
    if (CM & (1u << r)) {
      i32x4 b = *(const i32x4*)(base + 16384 + r * 2048 + wro);
#pragma unroll
      for (int i = 0; i < 4; ++i)
        acc[r][i] = __builtin_amdgcn_mfma_i32_16x16x64_i8(a[i], b, acc[r][i], 0, 0, 0);
    }
  }
  __builtin_amdgcn_s_setprio(0);
}

template<unsigned CM, unsigned SM, bool ST>
__device__ __forceinline__ void phase(char* lds, int h, const char* sAb, const char* sWb,
                                      int wid, int aro, int wro, i32x4 acc[4][4]) {
  if (ST) stage<SM>(lds, ((h + 1) & 1) * SLOT, h + 1, sAb, sWb, wid);
  comp<CM>(lds, (h & 1) * SLOT, aro, wro, acc);
  __syncthreads();
}

// ---------------- main fused kernel (4 gates i,f,k,o; 21 phases) ----------------
// acc[4][4] = 64 + arch ~56 <= 128/wave -> 4 waves/SIMD -> 2 full wgs/CU.
__global__ __launch_bounds__(512, 4) void lstm_main(
    const signed char* __restrict__ Ap, const signed char* __restrict__ Wp,
    const float* __restrict__ sa, const float* __restrict__ sw,
    const float* __restrict__ c_prev,
    const float* __restrict__ b_ix, const float* __restrict__ b_fx,
    const float* __restrict__ b_cx, const float* __restrict__ b_ox,
    float* __restrict__ out)
{
  __shared__ __align__(16) char lds[2 * SLOT];   // 49152 B -> 2 wgs/CU LDS-wise

  const int tid  = threadIdx.x;
  const int lane = tid & 63;
  const int wid  = tid >> 6;

  const int bid = blockIdx.x;
  const int xcd = bid & 7;
  const int idx = bid >> 3;                  // 0..127
  const int cb  = (xcd << 1) | (idx & 1);    // 0..15
  const int rb  = idx >> 1;                  // 0..63
  const unsigned brow = (unsigned)rb * 256u;
  const int bcol = cb * 32;

  const int wr  = (wid >> 1) * 64;           // wave rows [wr, wr+64)
  const int wcg = (wid & 1) * 16;            // wave cols [wcg, wcg+16)
  const int lrow = lane & 15;
  const int kgrp = lane >> 4;

  i32x4 acc[4][4];
  {
    i32x4 z = {0, 0, 0, 0};
#pragma unroll
    for (int g = 0; g < 4; ++g)
#pragma unroll
      for (int i = 0; i < 4; ++i) acc[g][i] = z;
  }

  const int sread = ((kgrp + (lrow >> 1)) & 3) << 4;
  const int aro = (wr + lrow) * 64 + sread;
  const int wro = (wcg + lrow) * 64 + sread;

  const int l4 = lane >> 2;
  const int kslot = (((lane & 3) - ((lane >> 3) & 3)) & 3) << 4;
  const char* sAb = (const char*)Ap + (size_t)(brow + wid * 32 + l4) * KPB + kslot;
  const char* sWb = (const char*)Wp + (size_t)(bcol + l4) * KPB + kslot;

  stage<0xF>(lds, 0, 0, sAb, sWb, wid);
  __syncthreads();

  // 21 phases: x+h ht0-11 (0xF) | c ht12-19 (0xB) | delt ht20 (0x8, o only)
#pragma unroll 1
  for (int h = 0; h < 11; ++h)
    phase<0xF, 0xF, true>(lds, h, sAb, sWb, wid, aro, wro, acc);
  phase<0xF, 0xB, true>(lds, 11, sAb, sWb, wid, aro, wro, acc);
#pragma unroll 1
  for (int h = 12; h < 19; ++h)
    phase<0xB, 0xB, true>(lds, h, sAb, sWb, wid, aro, wro, acc);
  phase<0xB, 0x8, true>(lds, 19, sAb, sWb, wid, aro, wro, acc);
  comp<0x8>(lds, (20 & 1) * SLOT, aro, wro, acc);

  // ---------------- fused epilogue (dequant + activations; Tv precomputed) ----------------
  const float* Tvp = out + 2 * BH;
  const int n = bcol + wcg + lrow;
  const float bi = b_ix[n], bff = b_fx[n], bc = b_cx[n], bo = b_ox[n];
  const float s0 = sw[0 * 512 + n], s1 = sw[1 * 512 + n];
  const float s3 = sw[3 * 512 + n], s4 = sw[4 * 512 + n];
  const int rbase = kgrp * 4;
#pragma unroll
  for (int i = 0; i < 4; ++i) {
    const int m0 = (int)brow + wr + 16 * i + rbase;
    const float4 sa4 = *(const float4*)(sa + m0);
#pragma unroll
    for (int r = 0; r < 4; ++r) {
      const long m   = m0 + r;
      const long off = m * H_SZ + n;
      const float sr = (r == 0) ? sa4.x : (r == 1) ? sa4.y : (r == 2) ? sa4.z : sa4.w;
      const float iv = sigm((float)acc[0][i][r] * sr * s0 + bi);
      const float fv = sigm((float)acc[1][i][r] * sr * s1 + bff);
      const float kv = tanhx((float)acc[2][i][r] * sr * s3 + bc);
      const float ov = sigm((float)acc[3][i][r] * sr * s4 + bo);
      const float Tv = Tvp[off];
      const float cp = c_prev[off];
      const float cn = iv * Tv * kv + fv * cp;
      out[off]      = ov * tanhx(cn);
      out[BH + off] = cn;
    }
  }
}

// ---------------- tgate: Tv = sigm(x@Wtx^T + b_tx + sigm(delt@Wtt^T)) -> out[2BH..] ----------
// regions {0,1} = gates {t=2, tt=5}; 5 phases (ht 0-3 x-seg, ht 20 delt-seg).
template<unsigned SMASK>
__device__ __forceinline__ void stage_t(char* lds, int sb, int ht,
                                        const char* sAb, const char* sWb, int wid) {
  const unsigned kb = (unsigned)ht * 64u;
  gld16(sAb + kb,              lds + sb + wid * 2048);
  gld16(sAb + kb + 16u * KPB,  lds + sb + wid * 2048 + 1024);
  if (wid < 4) {
    const int r = wid >> 1, c = wid & 1;
    if (SMASK & (1u << r)) {
      const int g = (r == 0) ? 2 : 5;
      gld16(sWb + (unsigned)g * GSTR + (unsigned)c * (16u * KPB) + kb,
            lds + sb + 16384 + r * 2048 + c * 1024);
    }
  }
}

template<unsigned CM>
__device__ __forceinline__ void comp_t(const char* lds, int sb, int aro, int wro,
                                       i32x4 acc[2][4]) {
  const char* base = lds + sb;
  i32x4 a[4];
#pragma unroll
  for (int i = 0; i < 4; ++i)
    a[i] = *(const i32x4*)(base + aro + i * 1024);
#pragma unroll
  for (int r = 0; r < 2; ++r) {
    if (CM & (1u << r)) {
      i32x4 b = *(const i32x4*)(base + 16384 + r * 2048 + wro);
#pragma unroll
      for (int i = 0; i < 4; ++i)
        acc[r][i] = __builtin_amdgcn_mfma_i32_16x16x64_i8(a[i], b, acc[r][i], 0, 0, 0);
    }
  }
}

__global__ __launch_bounds__(512, 4) void tgate_kernel(
    const signed char* __restrict__ Ap, const signed char* __restrict__ Wp,
    const float* __restrict__ sa, const float* __restrict__ sw,
    const float* __restrict__ b_tx, float* __restrict__ out)
{
  __shared__ __align__(16) char lds[2 * TSLOT];   // 40960 B

  const int tid  = threadIdx.x;
  const int lane = tid & 63;
  const int wid  = tid >> 6;

  const int bid = blockIdx.x;
  const int xcd = bid & 7;
  const int idx = bid >> 3;
  const int cb  = (xcd << 1) | (idx & 1);
  const int rb  = idx >> 1;
  const unsigned brow = (unsigned)rb * 256u;
  const int bcol = cb * 32;

  const int wr  = (wid >> 1) * 64;
  const int wcg = (wid & 1) * 16;
  const int lrow = lane & 15;
  const int kgrp = lane >> 4;

  i32x4 acc[2][4];
  {
    i32x4 z = {0, 0, 0, 0};
#pragma unroll
    for (int g = 0; g < 2; ++g)
#pragma unroll
      for (int i = 0; i < 4; ++i) acc[g][i] = z;
  }

  const int sread = ((kgrp + (lrow >> 1)) & 3) << 4;
  const int aro = (wr + lrow) * 64 + sread;
  const int wro = (wcg + lrow) * 64 + sread;

  const int l4 = lane >> 2;
  const int kslot = (((lane & 3) - ((lane >> 3) & 3)) & 3) << 4;
  const char* sAb = (const char*)Ap + (size_t)(brow + wid * 32 + l4) * KPB + kslot;
  const char* sWb = (const char*)Wp + (size_t)(bcol + l4) * KPB + kslot;

  stage_t<0x1>(lds, 0, 0, sAb, sWb, wid);
  __syncthreads();
  stage_t<0x1>(lds, TSLOT, 1, sAb, sWb, wid);
  comp_t<0x1>(lds, 0, aro, wro, acc);
  __syncthreads();
  stage_t<0x1>(lds, 0, 2, sAb, sWb, wid);
  comp_t<0x1>(lds, TSLOT, aro, wro, acc);
  __syncthreads();
  stage_t<0x1>(lds, TSLOT, 3, sAb, sWb, wid);
  comp_t<0x1>(lds, 0, aro, wro, acc);
  __syncthreads();
  stage_t<0x2>(lds, 0, 20, sAb, sWb, wid);     // delt segment (bytes 1280-1343)
  comp_t<0x1>(lds, TSLOT, aro, wro, acc);
  __syncthreads();
  comp_t<0x2>(lds, 0, aro, wro, acc);

  const int n = bcol + wcg + lrow;
  const float bt = b_tx[n];
  const float s2 = sw[2 * 512 + n], s5 = sw[5 * 512 + n];
  const int rbase = kgrp * 4;
#pragma unroll
  for (int i = 0; i < 4; ++i) {
    const int m0 = (int)brow + wr + 16 * i + rbase;
    const float4 sa4 = *(const float4*)(sa + m0);
#pragma unroll
    for (int r = 0; r < 4; ++r) {
      const long off = (long)(m0 + r) * H_SZ + n;
      const float sr = (r == 0) ? sa4.x : (r == 1) ? sa4.y : (r == 2) ? sa4.z : sa4.w;
      const float inner = sigm((float)acc[1][i][r] * sr * s5);
      out[2 * BH + off] = sigm((float)acc[0][i][r] * sr * s2 + bt + inner);
    }
  }
}

extern "C" void kernel_launch(void* const* d_in, const int* in_sizes, int n_in,
                              void* d_out, int out_size, void* d_ws, size_t ws_size,
                              hipStream_t stream) {
  const float* x      = (const float*)d_in[0];
  const float* h      = (const float*)d_in[1];
  const float* c_prev = (const float*)d_in[2];
  const float* dl     = (const float*)d_in[3];
  const float* W_ix = (const float*)d_in[4];
  const float* b_ix = (const float*)d_in[5];
  const float* W_ih = (const float*)d_in[6];
  const float* W_ic = (const float*)d_in[7];
  const float* W_fx = (const float*)d_in[8];
  const float* b_fx = (const float*)d_in[9];
  const float* W_fh = (const float*)d_in[10];
  const float* W_fc = (const float*)d_in[11];
  const float* W_tx = (const float*)d_in[12];
  const float* b_tx = (const float*)d_in[13];
  const float* W_tt = (const float*)d_in[14];
  const float* W_cx = (const float*)d_in[15];
  const float* b_cx = (const float*)d_in[16];
  const float* W_ch = (const float*)d_in[17];
  const float* W_ox = (const float*)d_in[18];
  const float* b_ox = (const float*)d_in[19];
  const float* W_oh = (const float*)d_in[20];
  const float* W_oc = (const float*)d_in[21];
  const float* W_ot = (const float*)d_in[22];

  signed char* Ap8 = (signed char*)d_ws;                             // 22,020,096 B
  signed char* Wp8 = (signed char*)d_ws + (size_t)B_SZ * KPB;        // + 4,128,768 B
  float* sa = (float*)((char*)d_ws + (size_t)B_SZ * KPB + 6L * H_SZ * KPB);   // 64 KB
  float* sw = sa + B_SZ;                                             // 12 KB

  prep_a8_kernel<<<B_SZ, 256, 0, stream>>>(x, h, c_prev, dl, Ap8, sa);
  prep_w8_kernel<<<6 * H_SZ, 256, 0, stream>>>(
      W_ix, W_ih, W_ic, W_fx, W_fh, W_fc, W_tx, W_tt, W_cx, W_ch,
      W_ox, W_oh, W_oc, W_ot, Wp8, sw);

  tgate_kernel<<<1024, 512, 0, stream>>>(Ap8, Wp8, sa, sw, b_tx, (float*)d_out);

  lstm_main<<<1024, 512, 0, stream>>>(Ap8, Wp8, sa, sw, c_prev,
                                      b_ix, b_fx, b_cx, b_ox,
                                      (float*)d_out);
}

// Round 18
// 115.740 us; speedup vs baseline: 1.1258x; 1.1258x over previous
//
#include <hip/hip_runtime.h>
#include <cstdint>

#define B_SZ   16384
#define H_SZ   512
#define DIN    256
#define TEMB   16
#define KP     1344            // packed K: x[0,256) h[256,768) c[768,1280) delt[1280,1296) pad
#define KPB    1344            // bytes per row (i8)
#define BH     8388608L        // B_SZ*H_SZ
#define SLOT   24576           // main slot: A 16 KB (256 rows x 64 B) + 4 W regions x 2 KB
#define TSLOT  20480           // tgate slot: A 16 KB + 2 W regions x 2 KB
#define GSTR   688128          // 512*KPB: gate stride in Wp8 bytes

typedef __attribute__((ext_vector_type(4))) float f32x4;
typedef __attribute__((ext_vector_type(4))) int   i32x4;

typedef const __attribute__((address_space(1))) unsigned int gu32_t;
typedef __attribute__((address_space(3)))       unsigned int lu32_t;

__device__ __forceinline__ void gld16(const void* g, void* l) {
  __builtin_amdgcn_global_load_lds((gu32_t*)(uintptr_t)g,
                                   (lu32_t*)(unsigned int)(uintptr_t)l, 16, 0, 0);
}

__device__ __forceinline__ float sigm(float v)  { return 1.0f / (1.0f + __expf(-v)); }
__device__ __forceinline__ float tanhx(float v) { return 2.0f / (1.0f + __expf(-2.0f * v)) - 1.0f; }

__device__ __forceinline__ signed char q8(float v, float inv) {
  int q = __float2int_rn(v * inv);
  q = (q > 127) ? 127 : (q < -127 ? -127 : q);
  return (signed char)q;
}

// ---------------- prep: quantize A rows (wave-per-row, no LDS/barriers) ----------------
__global__ void prep_a8_kernel(const float* __restrict__ x, const float* __restrict__ h,
                               const float* __restrict__ c, const float* __restrict__ dl,
                               signed char* __restrict__ Ap, float* __restrict__ sa) {
  const int tid  = threadIdx.x;
  const int lane = tid & 63;
  const int m    = blockIdx.x * 4 + (tid >> 6);   // 4096 blocks x 4 waves
  float4 v[6];
  float lmax = 0.f;
#pragma unroll
  for (int i = 0; i < 6; ++i) {
    const int k4 = (i * 64 + lane) * 4;
    float4 t = make_float4(0.f, 0.f, 0.f, 0.f);
    if (k4 < 256)       t = *(const float4*)(x  + (size_t)m * DIN  + k4);
    else if (k4 < 768)  t = *(const float4*)(h  + (size_t)m * H_SZ + (k4 - 256));
    else if (k4 < 1280) t = *(const float4*)(c  + (size_t)m * H_SZ + (k4 - 768));
    else if (k4 < 1296) t = *(const float4*)(dl + (size_t)m * TEMB + (k4 - 1280));
    v[i] = t;
    lmax = fmaxf(lmax, fmaxf(fmaxf(fabsf(t.x), fabsf(t.y)), fmaxf(fabsf(t.z), fabsf(t.w))));
  }
#pragma unroll
  for (int s = 1; s < 64; s <<= 1)
    lmax = fmaxf(lmax, __shfl_xor(lmax, s));
  const float smax = fmaxf(lmax, 1e-20f);
  const float inv  = 127.0f / smax;
  if (lane == 0) sa[m] = smax * (1.0f / 127.0f);
#pragma unroll
  for (int i = 0; i < 6; ++i) {
    const int k4 = (i * 64 + lane) * 4;
    if (k4 < KP) {
      char4 o;
      o.x = q8(v[i].x, inv); o.y = q8(v[i].y, inv);
      o.z = q8(v[i].z, inv); o.w = q8(v[i].w, inv);
      *(char4*)(Ap + (size_t)m * KPB + k4) = o;
    }
  }
}

// ---------------- prep: quantize Wp8[6][512][KP] i8 + per-row scale ----------------
__global__ void prep_w8_kernel(const float* __restrict__ Wix, const float* __restrict__ Wih, const float* __restrict__ Wic,
                               const float* __restrict__ Wfx, const float* __restrict__ Wfh, const float* __restrict__ Wfc,
                               const float* __restrict__ Wtx, const float* __restrict__ Wtt,
                               const float* __restrict__ Wcx, const float* __restrict__ Wch,
                               const float* __restrict__ Wox, const float* __restrict__ Woh,
                               const float* __restrict__ Woc, const float* __restrict__ Wot,
                               signed char* __restrict__ Wp, float* __restrict__ sw) {
  __shared__ float row[KP];
  __shared__ float red[256];
  const int R   = blockIdx.x;        // 0..3071
  const int g   = R >> 9;
  const int n   = R & 511;
  const int tid = threadIdx.x;
  float lmax = 0.f;
  for (int i = tid; i < KP / 4; i += 256) {
    const int k4 = i * 4;
    const float* src = nullptr; long o = 0;
    if (g == 0) {
      if (k4 < 256)       { src = Wix; o = (long)n * 256 + k4; }
      else if (k4 < 768)  { src = Wih; o = (long)n * 512 + (k4 - 256); }
      else if (k4 < 1280) { src = Wic; o = (long)n * 512 + (k4 - 768); }
    } else if (g == 1) {
      if (k4 < 256)       { src = Wfx; o = (long)n * 256 + k4; }
      else if (k4 < 768)  { src = Wfh; o = (long)n * 512 + (k4 - 256); }
      else if (k4 < 1280) { src = Wfc; o = (long)n * 512 + (k4 - 768); }
    } else if (g == 2) {
      if (k4 < 256)       { src = Wtx; o = (long)n * 256 + k4; }
    } else if (g == 3) {
      if (k4 < 256)       { src = Wcx; o = (long)n * 256 + k4; }
      else if (k4 < 768)  { src = Wch; o = (long)n * 512 + (k4 - 256); }
    } else if (g == 4) {
      if (k4 < 256)       { src = Wox; o = (long)n * 256 + k4; }
      else if (k4 < 768)  { src = Woh; o = (long)n * 512 + (k4 - 256); }
      else if (k4 < 1280) { src = Woc; o = (long)n * 512 + (k4 - 768); }
      else if (k4 < 1296) { src = Wot; o = (long)n * 16 + (k4 - 1280); }
    } else {
      if (k4 >= 1280 && k4 < 1296) { src = Wtt; o = (long)n * 16 + (k4 - 1280); }
    }
    float4 v = make_float4(0.f, 0.f, 0.f, 0.f);
    if (src) v = *(const float4*)(src + o);
    *(float4*)(row + k4) = v;
    lmax = fmaxf(lmax, fmaxf(fmaxf(fabsf(v.x), fabsf(v.y)), fmaxf(fabsf(v.z), fabsf(v.w))));
  }
  red[tid] = lmax;
  __syncthreads();
  for (int s = 128; s > 0; s >>= 1) {
    if (tid < s) red[tid] = fmaxf(red[tid], red[tid + s]);
    __syncthreads();
  }
  const float smax = fmaxf(red[0], 1e-20f);
  const float inv  = 127.0f / smax;
  if (tid == 0) sw[R] = smax * (1.0f / 127.0f);
  for (int i = tid; i < KP / 4; i += 256) {
    const int k4 = i * 4;
    char4 o;
    o.x = q8(row[k4],     inv); o.y = q8(row[k4 + 1], inv);
    o.z = q8(row[k4 + 2], inv); o.w = q8(row[k4 + 3], inv);
    *(char4*)(Wp + (size_t)R * KPB + k4) = o;
  }
}

// LDS layout per slot (K-phase = 64 i8 = 64 B per row; byte math r11/r16/r17-verified):
//   A: byte = row*64 + ((kgrp + (lrow>>1))&3)*16,  row in [0,256)
//   W: byte = 16384 + region*2048 + col*64 + swz,  col in [0,32)
// regions {0,1,2,3} = gates {i=0,f=1,k=3,o=4}; inactive K-segments in Wp are ZERO,
// so staging is mask-free (uniform 3 loads/wave -> compile-time vmcnt immediates).

__device__ __forceinline__ void stage(char* lds, int sb, int ht,
                                      const char* sAb, const char* sWb, int wid) {
  const unsigned kb = (unsigned)ht * 64u;
  gld16(sAb + kb,              lds + sb + wid * 2048);
  gld16(sAb + kb + 16u * KPB,  lds + sb + wid * 2048 + 1024);
  const int r = wid >> 1, c = wid & 1;        // region, col-half (wave-uniform)
  const int g = r + (r >> 1);                 // region -> gate: 0,1,3,4
  gld16(sWb + (unsigned)g * GSTR + (unsigned)c * (16u * KPB) + kb,
        lds + sb + 16384 + r * 2048 + c * 1024);
}

// single-barrier counted-vmcnt phase (ring-3, r14-proven template @ 2 wgs/CU):
//   vmcnt(NW): stage(h) landed (NW = in-flight count of stage(h+1) = 3, never 0
//   mid-loop); barrier publishes CU-wide; ds_reads(h); issue stage(h+2);
//   lgkmcnt(0)+sched_barrier (rule #18); pure MFMA cluster.
//   Ring-3 WAR safety: stage(h+2) writes slot (h-1)%3 whose readers drained
//   via their lgkmcnt(0) before reaching barrier(h).
template<unsigned CM, int NW, bool ST>
__device__ __forceinline__ void phase(char* lds, int rs, int ws, int ht,
    const char* sAb, const char* sWb, int wid, int aro, int wro, i32x4 acc[4][4]) {
  asm volatile("s_waitcnt vmcnt(%0)" :: "i"(NW) : "memory");
  __builtin_amdgcn_s_barrier();
  __builtin_amdgcn_sched_barrier(0);
  const char* base = lds + rs;
  i32x4 a[4];
#pragma unroll
  for (int i = 0; i < 4; ++i)
    a[i] = *(const i32x4*)(base + aro + i * 1024);
  i32x4 b[4];
#pragma unroll
  for (int r = 0; r < 4; ++r)
    if (CM & (1u << r))
      b[r] = *(const i32x4*)(base + 16384 + r * 2048 + wro);
  if (ST) stage(lds, ws, ht, sAb, sWb, wid);   // issue-only; rides vmcnt
  asm volatile("s_waitcnt lgkmcnt(0)" ::: "memory");
  __builtin_amdgcn_sched_barrier(0);
  __builtin_amdgcn_s_setprio(1);
#pragma unroll
  for (int r = 0; r < 4; ++r) {
    if (CM & (1u << r)) {
#pragma unroll
      for (int i = 0; i < 4; ++i)
        acc[r][i] = __builtin_amdgcn_mfma_i32_16x16x64_i8(a[i], b[r], acc[r][i], 0, 0, 0);
    }
  }
  __builtin_amdgcn_s_setprio(0);
}

// ---------------- main fused kernel (4 gates i,f,k,o; 21 phases, ring-3) ----------------
// acc[4][4]=64 + arch ~56 <= 128/wave -> 4 waves/SIMD; LDS 3*24576*2 = 147456 <= 160K.
__global__ __launch_bounds__(512, 4) void lstm_main(
    const signed char* __restrict__ Ap, const signed char* __restrict__ Wp,
    const float* __restrict__ sa, const float* __restrict__ sw,
    const float* __restrict__ c_prev,
    const float* __restrict__ b_ix, const float* __restrict__ b_fx,
    const float* __restrict__ b_cx, const float* __restrict__ b_ox,
    float* __restrict__ out)
{
  __shared__ __align__(16) char lds[3 * SLOT];   // 73728 B -> 2 wgs/CU

  const int tid  = threadIdx.x;
  const int lane = tid & 63;
  const int wid  = tid >> 6;

  const int bid = blockIdx.x;
  const int xcd = bid & 7;
  const int idx = bid >> 3;                  // 0..127
  const int cb  = (xcd << 1) | (idx & 1);    // 0..15
  const int rb  = idx >> 1;                  // 0..63
  const unsigned brow = (unsigned)rb * 256u;
  const int bcol = cb * 32;

  const int wr  = (wid >> 1) * 64;           // wave rows [wr, wr+64)
  const int wcg = (wid & 1) * 16;            // wave cols [wcg, wcg+16)
  const int lrow = lane & 15;
  const int kgrp = lane >> 4;

  i32x4 acc[4][4];
  {
    i32x4 z = {0, 0, 0, 0};
#pragma unroll
    for (int g = 0; g < 4; ++g)
#pragma unroll
      for (int i = 0; i < 4; ++i) acc[g][i] = z;
  }

  const int sread = ((kgrp + (lrow >> 1)) & 3) << 4;
  const int aro = (wr + lrow) * 64 + sread;
  const int wro = (wcg + lrow) * 64 + sread;

  const int l4 = lane >> 2;
  const int kslot = (((lane & 3) - ((lane >> 3) & 3)) & 3) << 4;
  const char* sAb = (const char*)Ap + (size_t)(brow + wid * 32 + l4) * KPB + kslot;
  const char* sWb = (const char*)Wp + (size_t)(bcol + l4) * KPB + kslot;

  // prologue: half-tiles 0,1 in flight
  stage(lds, 0,    0, sAb, sWb, wid);
  stage(lds, SLOT, 1, sAb, sWb, wid);

  int rs = 0;
#define PH(CMv, NWv, STv, HT) do {                                             \
    int ws = (rs >= SLOT) ? rs - SLOT : rs + 2 * SLOT;                         \
    phase<CMv, NWv, STv>(lds, rs, ws, HT, sAb, sWb, wid, aro, wro, acc);       \
    rs = (rs == 2 * SLOT) ? 0 : rs + SLOT;                                     \
  } while (0)

  // comp masks: ht0-11 x+h (0xF) | ht12-19 c (0xB) | ht20 delt (0x8)
#pragma unroll 1
  for (int h = 0; h < 11; ++h) PH(0xF, 3, true, h + 2);
  PH(0xF, 3, true, 13);
#pragma unroll 1
  for (int h = 12; h < 19; ++h) PH(0xB, 3, true, h + 2);
  PH(0xB, 3, false, 0);    // h=19: stage(20) still in flight -> vmcnt(3)
  PH(0x8, 0, false, 0);    // h=20: drain
#undef PH

  // ---------------- fused epilogue (dequant + activations; Tv precomputed) ----------------
  const float* Tvp = out + 2 * BH;
  const int n = bcol + wcg + lrow;
  const float bi = b_ix[n], bff = b_fx[n], bc = b_cx[n], bo = b_ox[n];
  const float s0 = sw[0 * 512 + n], s1 = sw[1 * 512 + n];
  const float s3 = sw[3 * 512 + n], s4 = sw[4 * 512 + n];
  const int rbase = kgrp * 4;
#pragma unroll
  for (int i = 0; i < 4; ++i) {
    const int m0 = (int)brow + wr + 16 * i + rbase;
    const float4 sa4 = *(const float4*)(sa + m0);
#pragma unroll
    for (int r = 0; r < 4; ++r) {
      const long m   = m0 + r;
      const long off = m * H_SZ + n;
      const float sr = (r == 0) ? sa4.x : (r == 1) ? sa4.y : (r == 2) ? sa4.z : sa4.w;
      const float iv = sigm((float)acc[0][i][r] * sr * s0 + bi);
      const float fv = sigm((float)acc[1][i][r] * sr * s1 + bff);
      const float kv = tanhx((float)acc[2][i][r] * sr * s3 + bc);
      const float ov = sigm((float)acc[3][i][r] * sr * s4 + bo);
      const float Tv = Tvp[off];
      const float cp = c_prev[off];
      const float cn = iv * Tv * kv + fv * cp;
      out[off]      = ov * tanhx(cn);
      out[BH + off] = cn;
    }
  }
}

// ---------------- tgate: Tv = sigm(x@Wtx^T + b_tx + sigm(delt@Wtt^T)) -> out[2BH..] ----------
template<unsigned SMASK>
__device__ __forceinline__ void stage_t(char* lds, int sb, int ht,
                                        const char* sAb, const char* sWb, int wid) {
  const unsigned kb = (unsigned)ht * 64u;
  gld16(sAb + kb,              lds + sb + wid * 2048);
  gld16(sAb + kb + 16u * KPB,  lds + sb + wid * 2048 + 1024);
  if (wid < 4) {
    const int r = wid >> 1, c = wid & 1;
    if (SMASK & (1u << r)) {
      const int g = (r == 0) ? 2 : 5;
      gld16(sWb + (unsigned)g * GSTR + (unsigned)c * (16u * KPB) + kb,
            lds + sb + 16384 + r * 2048 + c * 1024);
    }
  }
}

template<unsigned CM>
__device__ __forceinline__ void comp_t(const char* lds, int sb, int aro, int wro,
                                       i32x4 acc[2][4]) {
  const char* base = lds + sb;
  i32x4 a[4];
#pragma unroll
  for (int i = 0; i < 4; ++i)
    a[i] = *(const i32x4*)(base + aro + i * 1024);
#pragma unroll
  for (int r = 0; r < 2; ++r) {
    if (CM & (1u << r)) {
      i32x4 b = *(const i32x4*)(base + 16384 + r * 2048 + wro);
#pragma unroll
      for (int i = 0; i < 4; ++i)
        acc[r][i] = __builtin_amdgcn_mfma_i32_16x16x64_i8(a[i], b, acc[r][i], 0, 0, 0);
    }
  }
}

__global__ __launch_bounds__(512, 4) void tgate_kernel(
    const signed char* __restrict__ Ap, const signed char* __restrict__ Wp,
    const float* __restrict__ sa, const float* __restrict__ sw,
    const float* __restrict__ b_tx, float* __restrict__ out)
{
  __shared__ __align__(16) char lds[2 * TSLOT];   // 40960 B

  const int tid  = threadIdx.x;
  const int lane = tid & 63;
  const int wid  = tid >> 6;

  const int bid = blockIdx.x;
  const int xcd = bid & 7;
  const int idx = bid >> 3;
  const int cb  = (xcd << 1) | (idx & 1);
  const int rb  = idx >> 1;
  const unsigned brow = (unsigned)rb * 256u;
  const int bcol = cb * 32;

  const int wr  = (wid >> 1) * 64;
  const int wcg = (wid & 1) * 16;
  const int lrow = lane & 15;
  const int kgrp = lane >> 4;

  i32x4 acc[2][4];
  {
    i32x4 z = {0, 0, 0, 0};
#pragma unroll
    for (int g = 0; g < 2; ++g)
#pragma unroll
      for (int i = 0; i < 4; ++i) acc[g][i] = z;
  }

  const int sread = ((kgrp + (lrow >> 1)) & 3) << 4;
  const int aro = (wr + lrow) * 64 + sread;
  const int wro = (wcg + lrow) * 64 + sread;

  const int l4 = lane >> 2;
  const int kslot = (((lane & 3) - ((lane >> 3) & 3)) & 3) << 4;
  const char* sAb = (const char*)Ap + (size_t)(brow + wid * 32 + l4) * KPB + kslot;
  const char* sWb = (const char*)Wp + (size_t)(bcol + l4) * KPB + kslot;

  stage_t<0x1>(lds, 0, 0, sAb, sWb, wid);
  __syncthreads();
  stage_t<0x1>(lds, TSLOT, 1, sAb, sWb, wid);
  comp_t<0x1>(lds, 0, aro, wro, acc);
  __syncthreads();
  stage_t<0x1>(lds, 0, 2, sAb, sWb, wid);
  comp_t<0x1>(lds, TSLOT, aro, wro, acc);
  __syncthreads();
  stage_t<0x1>(lds, TSLOT, 3, sAb, sWb, wid);
  comp_t<0x1>(lds, 0, aro, wro, acc);
  __syncthreads();
  stage_t<0x2>(lds, 0, 20, sAb, sWb, wid);     // delt segment (bytes 1280-1343)
  comp_t<0x1>(lds, TSLOT, aro, wro, acc);
  __syncthreads();
  comp_t<0x2>(lds, 0, aro, wro, acc);

  const int n = bcol + wcg + lrow;
  const float bt = b_tx[n];
  const float s2 = sw[2 * 512 + n], s5 = sw[5 * 512 + n];
  const int rbase = kgrp * 4;
#pragma unroll
  for (int i = 0; i < 4; ++i) {
    const int m0 = (int)brow + wr + 16 * i + rbase;
    const float4 sa4 = *(const float4*)(sa + m0);
#pragma unroll
    for (int r = 0; r < 4; ++r) {
      const long off = (long)(m0 + r) * H_SZ + n;
      const float sr = (r == 0) ? sa4.x : (r == 1) ? sa4.y : (r == 2) ? sa4.z : sa4.w;
      const float inner = sigm((float)acc[1][i][r] * sr * s5);
      out[2 * BH + off] = sigm((float)acc[0][i][r] * sr * s2 + bt + inner);
    }
  }
}

extern "C" void kernel_launch(void* const* d_in, const int* in_sizes, int n_in,
                              void* d_out, int out_size, void* d_ws, size_t ws_size,
                              hipStream_t stream) {
  const float* x      = (const float*)d_in[0];
  const float* h      = (const float*)d_in[1];
  const float* c_prev = (const float*)d_in[2];
  const float* dl     = (const float*)d_in[3];
  const float* W_ix = (const float*)d_in[4];
  const float* b_ix = (const float*)d_in[5];
  const float* W_ih = (const float*)d_in[6];
  const float* W_ic = (const float*)d_in[7];
  const float* W_fx = (const float*)d_in[8];
  const float* b_fx = (const float*)d_in[9];
  const float* W_fh = (const float*)d_in[10];
  const float* W_fc = (const float*)d_in[11];
  const float* W_tx = (const float*)d_in[12];
  const float* b_tx = (const float*)d_in[13];
  const float* W_tt = (const float*)d_in[14];
  const float* W_cx = (const float*)d_in[15];
  const float* b_cx = (const float*)d_in[16];
  const float* W_ch = (const float*)d_in[17];
  const float* W_ox = (const float*)d_in[18];
  const float* b_ox = (const float*)d_in[19];
  const float* W_oh = (const float*)d_in[20];
  const float* W_oc = (const float*)d_in[21];
  const float* W_ot = (const float*)d_in[22];

  signed char* Ap8 = (signed char*)d_ws;                             // 22,020,096 B
  signed char* Wp8 = (signed char*)d_ws + (size_t)B_SZ * KPB;        // + 4,128,768 B
  float* sa = (float*)((char*)d_ws + (size_t)B_SZ * KPB + 6L * H_SZ * KPB);   // 64 KB
  float* sw = sa + B_SZ;                                             // 12 KB

  prep_a8_kernel<<<B_SZ / 4, 256, 0, stream>>>(x, h, c_prev, dl, Ap8, sa);
  prep_w8_kernel<<<6 * H_SZ, 256, 0, stream>>>(
      W_ix, W_ih, W_ic, W_fx, W_fh, W_fc, W_tx, W_tt, W_cx, W_ch,
      W_ox, W_oh, W_oc, W_ot, Wp8, sw);

  tgate_kernel<<<1024, 512, 0, stream>>>(Ap8, Wp8, sa, sw, b_tx, (float*)d_out);

  lstm_main<<<1024, 512, 0, stream>>>(Ap8, Wp8, sa, sw, c_prev,
                                      b_ix, b_fx, b_cx, b_ox,
                                      (float*)d_out);
}